// Round 2
// baseline (1144.555 us; speedup 1.0000x reference)
//
#include <hip/hip_runtime.h>
#include <cstdint>
#include <cstddef>

#define B_  64
#define NI  2048
#define DI  16
#define NO  32
#define DO  32
#define JD  1024   // NO*DO
#define BT  8      // batches per block
#define IT  16     // i's per block
#define EPSQ 1e-9f

// 16B-granular XOR swizzle: spreads 64-lane reads of 64B-stride rows across
// all 32 LDS banks (bits [6:4] ^= bits [10:8]). Involution; 16B-align preserved.
__device__ __forceinline__ int swz(int lin) {
  return lin ^ (((lin >> 8) & 7) << 4);
}

// One recompute pass over u_hat.
// ROUTE=false:  sout[b,jd] += sum_i u_hat[b,i,jd]                  (for U)
// ROUTE=true :  a[b,i,j] = sum_d u_hat*vin ; c = softmax_j(a);
//               sout[b,jd] += sum_i c[b,i,j] * u_hat[b,i,jd]
template<bool ROUTE>
__global__ __launch_bounds__(256, 2)
void pass_kernel(const float* __restrict__ x, const float* __restrict__ W,
                 const float* __restrict__ vin, float* __restrict__ sout)
{
  __shared__ float wlds[JD * DI];        // 64 KB, swizzled
  __shared__ float xlds[BT][IT * DI];    // 8 KB
  __shared__ float alds[BT][NO];
  __shared__ float clds[BT][NO];

  const int t   = threadIdx.x;
  const int i0  = blockIdx.x * IT;
  const int b0  = blockIdx.y * BT;
  const int jd0 = t << 2;                // 4 consecutive (j,d) per thread
  const int j   = t >> 3;                // 8 threads cover the 32 d's of one j

  float vreg[BT][4];
  if constexpr (ROUTE) {
    #pragma unroll
    for (int b = 0; b < BT; ++b) {
      const float4 vv = *reinterpret_cast<const float4*>(vin + (size_t)(b0 + b) * JD + jd0);
      vreg[b][0] = vv.x; vreg[b][1] = vv.y; vreg[b][2] = vv.z; vreg[b][3] = vv.w;
    }
  }

  // stage x[b0..b0+7][i0..i0+15][0..15] once (coalesced float4)
  for (int c = t; c < BT * IT * DI / 4; c += 256) {
    const int b = c >> 6;        // 64 float4 per batch row
    const int r = c & 63;
    *reinterpret_cast<float4*>(&xlds[b][r << 2]) =
      *reinterpret_cast<const float4*>(x + (size_t)(b0 + b) * NI * DI + (size_t)i0 * DI + (r << 2));
  }

  float sacc[BT][4];
  #pragma unroll
  for (int b = 0; b < BT; ++b)
    for (int dd = 0; dd < 4; ++dd) sacc[b][dd] = 0.0f;

  for (int ii = 0; ii < IT; ++ii) {
    __syncthreads();   // previous iter's wlds/clds reads done
    // ---- stage W_i (16384 floats) swizzled, coalesced float4 ----
    const float4* wg = reinterpret_cast<const float4*>(W + (size_t)(i0 + ii) * (JD * DI));
    #pragma unroll
    for (int c = 0; c < 16; ++c) {
      const int f4 = t + (c << 8);
      *reinterpret_cast<float4*>(reinterpret_cast<char*>(wlds) + swz(f4 << 4)) = wg[f4];
    }
    __syncthreads();

    // ---- u_hat[b][dd] = sum_k W[jd0+dd][k] * x[b][k] ----
    float u[BT][4];
    #pragma unroll
    for (int b = 0; b < BT; ++b)
      for (int dd = 0; dd < 4; ++dd) u[b][dd] = 0.0f;

    #pragma unroll
    for (int k4 = 0; k4 < 4; ++k4) {
      float4 wr[4];
      #pragma unroll
      for (int dd = 0; dd < 4; ++dd) {
        const int lin = ((jd0 + dd) << 6) + (k4 << 4);   // row*64B + chunk*16B
        wr[dd] = *reinterpret_cast<const float4*>(reinterpret_cast<const char*>(wlds) + swz(lin));
      }
      #pragma unroll
      for (int b = 0; b < BT; ++b) {
        const float4 xr = *reinterpret_cast<const float4*>(&xlds[b][ii * DI + (k4 << 2)]);
        #pragma unroll
        for (int dd = 0; dd < 4; ++dd)
          u[b][dd] += wr[dd].x * xr.x + wr[dd].y * xr.y + wr[dd].z * xr.z + wr[dd].w * xr.w;
      }
    }

    if constexpr (ROUTE) {
      // agreement logits: a[b,j] = sum_d u_hat * v
      float ap[BT];
      #pragma unroll
      for (int b = 0; b < BT; ++b)
        ap[b] = u[b][0]*vreg[b][0] + u[b][1]*vreg[b][1] + u[b][2]*vreg[b][2] + u[b][3]*vreg[b][3];
      #pragma unroll
      for (int s = 1; s < 8; s <<= 1)
        #pragma unroll
        for (int b = 0; b < BT; ++b) ap[b] += __shfl_xor(ap[b], s, 64);
      if ((t & 7) == 0)
        #pragma unroll
        for (int b = 0; b < BT; ++b) alds[b][j] = ap[b];
      __syncthreads();
      // cooperative softmax: 256 threads = 8 b x 32 j, width-32 butterfly
      {
        const int bb = t >> 5, jj = t & 31;
        const float av = alds[bb][jj];
        float m = av;
        #pragma unroll
        for (int s = 1; s < 32; s <<= 1) m = fmaxf(m, __shfl_xor(m, s, 32));
        const float e = __expf(av - m);
        float den = e;
        #pragma unroll
        for (int s = 1; s < 32; s <<= 1) den += __shfl_xor(den, s, 32);
        clds[bb][jj] = e / den;
      }
      __syncthreads();
      #pragma unroll
      for (int b = 0; b < BT; ++b) {
        const float cv = clds[b][j];
        #pragma unroll
        for (int dd = 0; dd < 4; ++dd) sacc[b][dd] += cv * u[b][dd];
      }
    } else {
      #pragma unroll
      for (int b = 0; b < BT; ++b)
        for (int dd = 0; dd < 4; ++dd) sacc[b][dd] += u[b][dd];
    }
  }

  #pragma unroll
  for (int b = 0; b < BT; ++b) {
    float* p = sout + (size_t)(b0 + b) * JD + jd0;
    atomicAdd(p + 0, sacc[b][0]);
    atomicAdd(p + 1, sacc[b][1]);
    atomicAdd(p + 2, sacc[b][2]);
    atomicAdd(p + 3, sacc[b][3]);
  }
}

// out = squash(scale * sin)  [+ vprev].  One width-32 group per (b,j) row.
__global__ void squash_kernel(const float* __restrict__ sin_, const float* __restrict__ vprev,
                              float* __restrict__ out, float scale, int addPrev)
{
  const int t = blockIdx.x * 256 + threadIdx.x;   // 0..65535 = b*1024 + j*32 + d
  const float val = sin_[t] * scale;
  float sq = val * val;
  #pragma unroll
  for (int s = 1; s < 32; s <<= 1) sq += __shfl_xor(sq, s, 32);
  const float f = sq / ((1.0f + sq + EPSQ) * sqrtf(sq + EPSQ));
  float o = f * val;
  if (addPrev) o += vprev[t];
  out[t] = o;
}

extern "C" void kernel_launch(void* const* d_in, const int* in_sizes, int n_in,
                              void* d_out, int out_size, void* d_ws, size_t ws_size,
                              hipStream_t stream) {
  const float* x = (const float*)d_in[0];
  const float* W = (const float*)d_in[1];
  float* ws = (float*)d_ws;
  float* U  = ws;                 // [64,1024]
  float* s1 = ws + 65536;
  float* s2 = ws + 131072;
  float* v0 = ws + 196608;
  float* vs = ws + 262144;        // v0 + v1
  float* out = (float*)d_out;

  hipMemsetAsync(ws, 0, (size_t)3 * 65536 * sizeof(float), stream);  // zero U, s1, s2

  dim3 grid(NI / IT, B_ / BT);
  // iter 0: c uniform -> U = sum_i u_hat, v0 = squash(U/32)
  pass_kernel<false><<<grid, 256, 0, stream>>>(x, W, nullptr, U);
  squash_kernel<<<256, 256, 0, stream>>>(U, nullptr, v0, 1.0f / 32.0f, 0);
  // iter 1: b1 = uhat.v0 ; s1 = sum c1*uhat ; vs = v0 + squash(s1)
  pass_kernel<true><<<grid, 256, 0, stream>>>(x, W, v0, s1);
  squash_kernel<<<256, 256, 0, stream>>>(s1, v0, vs, 1.0f, 1);
  // iter 2: b2 = uhat.(v0+v1) ; s2 = sum c2*uhat ; out = squash(s2)
  pass_kernel<true><<<grid, 256, 0, stream>>>(x, W, vs, s2);
  squash_kernel<<<256, 256, 0, stream>>>(s2, nullptr, out, 1.0f, 0);
}

// Round 3
// 633.107 us; speedup vs baseline: 1.8078x; 1.8078x over previous
//
#include <hip/hip_runtime.h>
#include <cstdint>
#include <cstddef>

#define B_  64
#define NI  2048
#define DI  16
#define NO  32
#define DO  32
#define JD  1024   // NO*DO
#define BT  8      // batches per block
#define IT  16     // i's per block
#define NBX (NI/IT)  // 128 partial slices
#define EPSQ 1e-9f

// One recompute pass over u_hat. Thread owns 2 consecutive jd rows (jd0 = 2t).
// W is read straight from global (one 128B line per thread per i, zero
// cross-thread reuse -> no LDS staging). x reads are block-uniform (compiler
// can scalarize). LDS only holds the 2KB softmax scratch.
// ROUTE=false:  sout <- sum_i u_hat
// ROUTE=true :  a = u_hat . vin ; c = softmax_j(a) ; sout <- sum_i c*u_hat
// PARTIAL=true: single-writer partial per blockIdx.x slice (no atomics).
template<bool ROUTE, bool PARTIAL>
__global__ __launch_bounds__(512, 4)
void pass_kernel(const float* __restrict__ x, const float* __restrict__ W,
                 const float* __restrict__ vin, float* __restrict__ sout)
{
  __shared__ float alds[BT][NO];
  __shared__ float clds[BT][NO];

  const int t   = threadIdx.x;       // 0..511
  const int i0  = blockIdx.x * IT;
  const int b0  = blockIdx.y * BT;
  const int jd0 = t << 1;            // 2 rows per thread
  const int j   = t >> 4;            // 16 threads cover the 32 d's of one j

  float2 vreg[BT];
  if constexpr (ROUTE) {
    #pragma unroll
    for (int b = 0; b < BT; ++b)
      vreg[b] = *reinterpret_cast<const float2*>(vin + (size_t)(b0 + b) * JD + jd0);
  }

  float2 sacc[BT];
  #pragma unroll
  for (int b = 0; b < BT; ++b) sacc[b] = make_float2(0.f, 0.f);

  for (int ii = 0; ii < IT; ++ii) {
    // ---- W rows jd0, jd0+1 of capsule i0+ii: 8 x float4 = 128B (1 line) ----
    const float4* wf = reinterpret_cast<const float4*>(W + (size_t)(i0 + ii) * (JD * DI));
    float4 wr0[4], wr1[4];
    #pragma unroll
    for (int k4 = 0; k4 < 4; ++k4) {
      wr0[k4] = wf[(jd0    ) * 4 + k4];
      wr1[k4] = wf[(jd0 + 1) * 4 + k4];
    }

    // ---- u_hat for 8 batches x 2 rows (x loads are block-uniform) ----
    float u0[BT], u1[BT];
    #pragma unroll
    for (int b = 0; b < BT; ++b) { u0[b] = 0.f; u1[b] = 0.f; }
    #pragma unroll
    for (int k4 = 0; k4 < 4; ++k4) {
      #pragma unroll
      for (int b = 0; b < BT; ++b) {
        const float4 xv = *reinterpret_cast<const float4*>(
            x + (size_t)(b0 + b) * (NI * DI) + (size_t)(i0 + ii) * DI + (k4 << 2));
        u0[b] += wr0[k4].x*xv.x + wr0[k4].y*xv.y + wr0[k4].z*xv.z + wr0[k4].w*xv.w;
        u1[b] += wr1[k4].x*xv.x + wr1[k4].y*xv.y + wr1[k4].z*xv.z + wr1[k4].w*xv.w;
      }
    }

    if constexpr (ROUTE) {
      // logits a[b,j] = sum_d u_hat*v : partial per thread, reduce over 16 lanes
      float ap[BT];
      #pragma unroll
      for (int b = 0; b < BT; ++b)
        ap[b] = u0[b]*vreg[b].x + u1[b]*vreg[b].y;
      #pragma unroll
      for (int s = 1; s < 16; s <<= 1) {
        #pragma unroll
        for (int b = 0; b < BT; ++b) ap[b] += __shfl_xor(ap[b], s, 16);
      }
      if ((t & 15) == 0) {
        #pragma unroll
        for (int b = 0; b < BT; ++b) alds[b][j] = ap[b];
      }
      __syncthreads();
      // cooperative softmax over j: threads 0..255 = 8 b x 32 j
      if (t < BT * NO) {
        const int bb = t >> 5, jj = t & 31;
        const float av = alds[bb][jj];
        float m = av;
        #pragma unroll
        for (int s = 1; s < 32; s <<= 1) m = fmaxf(m, __shfl_xor(m, s, 32));
        const float e = __expf(av - m);
        float den = e;
        #pragma unroll
        for (int s = 1; s < 32; s <<= 1) den += __shfl_xor(den, s, 32);
        clds[bb][jj] = e / den;
      }
      __syncthreads();
      #pragma unroll
      for (int b = 0; b < BT; ++b) {
        const float cv = clds[b][j];
        sacc[b].x += cv * u0[b];
        sacc[b].y += cv * u1[b];
      }
    } else {
      #pragma unroll
      for (int b = 0; b < BT; ++b) { sacc[b].x += u0[b]; sacc[b].y += u1[b]; }
    }
  }

  #pragma unroll
  for (int b = 0; b < BT; ++b) {
    if constexpr (PARTIAL) {
      // part[blockIdx.x][b_abs][jd] : single writer, no atomics, no zeroing
      *reinterpret_cast<float2*>(
          sout + ((size_t)(blockIdx.x * B_ + b0 + b) << 10) + jd0) = sacc[b];
    } else {
      float* p = sout + (size_t)(b0 + b) * JD + jd0;
      atomicAdd(p + 0, sacc[b].x);
      atomicAdd(p + 1, sacc[b].y);
    }
  }
}

// out[b,jd] = squash over d of (scale * sum_p part[p][b][jd]) [+ vprev]
// grid = 64 blocks (one per b), 1024 threads (one per jd).
__global__ void reduce_squash(const float* __restrict__ part, int nPart,
                              const float* __restrict__ vprev,
                              float* __restrict__ out, float scale, int addPrev)
{
  const int b  = blockIdx.x;
  const int jd = threadIdx.x;
  float s = 0.f;
  for (int p = 0; p < nPart; ++p)
    s += part[((size_t)(p * B_ + b) << 10) + jd];
  const float val = s * scale;
  float sq = val * val;
  #pragma unroll
  for (int w = 1; w < 32; w <<= 1) sq += __shfl_xor(sq, w, 32);
  const float f = sq / ((1.0f + sq + EPSQ) * sqrtf(sq + EPSQ));
  float o = f * val;
  if (addPrev) o += vprev[b * JD + jd];
  out[b * JD + jd] = o;
}

extern "C" void kernel_launch(void* const* d_in, const int* in_sizes, int n_in,
                              void* d_out, int out_size, void* d_ws, size_t ws_size,
                              hipStream_t stream) {
  const float* x = (const float*)d_in[0];
  const float* W = (const float*)d_in[1];
  float* ws  = (float*)d_ws;
  float* out = (float*)d_out;

  const size_t needPartial = ((size_t)NBX * B_ * JD + 2u * B_ * JD) * sizeof(float);
  const dim3 grid(NBX, B_ / BT);

  if (ws_size >= needPartial) {
    float* part = ws;                        // [128][64][1024]
    float* v0   = ws + (size_t)NBX * B_ * JD;
    float* vs   = v0 + B_ * JD;
    pass_kernel<false, true><<<grid, 512, 0, stream>>>(x, W, nullptr, part);
    reduce_squash<<<B_, JD, 0, stream>>>(part, NBX, nullptr, v0, 1.0f / 32.0f, 0);
    pass_kernel<true, true><<<grid, 512, 0, stream>>>(x, W, v0, part);
    reduce_squash<<<B_, JD, 0, stream>>>(part, NBX, v0, vs, 1.0f, 1);
    pass_kernel<true, true><<<grid, 512, 0, stream>>>(x, W, vs, part);
    reduce_squash<<<B_, JD, 0, stream>>>(part, NBX, nullptr, out, 1.0f, 0);
  } else {
    float* s  = ws;                          // [64][1024] atomic accumulator
    float* v0 = ws + B_ * JD;
    float* vs = v0 + B_ * JD;
    hipMemsetAsync(s, 0, (size_t)B_ * JD * sizeof(float), stream);
    pass_kernel<false, false><<<grid, 512, 0, stream>>>(x, W, nullptr, s);
    reduce_squash<<<B_, JD, 0, stream>>>(s, 1, nullptr, v0, 1.0f / 32.0f, 0);
    hipMemsetAsync(s, 0, (size_t)B_ * JD * sizeof(float), stream);
    pass_kernel<true, false><<<grid, 512, 0, stream>>>(x, W, v0, s);
    reduce_squash<<<B_, JD, 0, stream>>>(s, 1, v0, vs, 1.0f, 1);
    hipMemsetAsync(s, 0, (size_t)B_ * JD * sizeof(float), stream);
    pass_kernel<true, false><<<grid, 512, 0, stream>>>(x, W, vs, s);
    reduce_squash<<<B_, JD, 0, stream>>>(s, 1, nullptr, out, 1.0f, 0);
  }
}

// Round 4
// 398.153 us; speedup vs baseline: 2.8747x; 1.5901x over previous
//
#include <hip/hip_runtime.h>
#include <cstdint>
#include <cstddef>

#define B_   64
#define NI   2048
#define DI   16
#define NO   32
#define JD   1024          // NO*DO
#define IT   16            // capsules-in per block
#define NBX  (NI/IT)       // 128 partial slices
#define XSTR 260           // x_lds row stride (u32); 260*4=1040 B, 16B-aligned, 4b%32 bank spread
#define EPSQ 1e-9f

typedef __attribute__((ext_vector_type(8)))  short bf16x8;
typedef __attribute__((ext_vector_type(16))) float f32x16;

// truncation split: w == hi + lo + O(2^-16 w); returns packed (hi16<<16)|lo16
__device__ __forceinline__ uint32_t pack_split(float w) {
  uint32_t u = __float_as_uint(w);
  float hf = __uint_as_float(u & 0xffff0000u);
  uint32_t lo = __float_as_uint(w - hf) >> 16;
  return (u & 0xffff0000u) | lo;
}

__device__ __forceinline__ void cvt8(const float4 a, const float4 b, bf16x8& h8, bf16x8& l8) {
  float w[8] = {a.x, a.y, a.z, a.w, b.x, b.y, b.z, b.w};
  #pragma unroll
  for (int e = 0; e < 8; ++e) {
    uint32_t u = __float_as_uint(w[e]);
    float hf = __uint_as_float(u & 0xffff0000u);
    h8[e] = (short)(u >> 16);
    l8[e] = (short)(__float_as_uint(w[e] - hf) >> 16);
  }
}

__device__ __forceinline__ f32x16 zero16() {
  f32x16 z;
  #pragma unroll
  for (int r = 0; r < 16; ++r) z[r] = 0.0f;
  return z;
}

// One recompute pass. Block: 512 thr = 8 waves; wave wv owns jd rows [wv*128, wv*128+128)
// as 4 MFMA 32x32 M-tiles; N = 32 batches (blockIdx.y half). K=16=DI exact.
// u = Whi*xhi + Whi*xlo + Wlo*xhi (compensated bf16, err ~1e-4).
// ROUTE: per-i agreement a=u.v, softmax_j via LDS, s += c*u.  else: s += u.
template<bool ROUTE>
__global__ __launch_bounds__(512, 2)
void caps_pass(const float* __restrict__ x, const float* __restrict__ W,
               const float* __restrict__ vin, float* __restrict__ part)
{
  __shared__ uint32_t xl[32 * XSTR];   // x, packed bf16 hi|lo
  __shared__ float al[NO * 32];        // logits  [j][rot(b)]
  __shared__ float cl[NO * 32];        // softmax [j][rot(b)]

  const int t    = threadIdx.x;
  const int wv   = t >> 6;
  const int l    = t & 63;
  const int col  = l & 31;             // = output b within the 32-batch half (C: col=lane&31)
  const int hb   = l >> 5;
  const int p    = blockIdx.x;         // i-chunk
  const int half = blockIdx.y;         // batch half
  const int i0   = p * IT;
  const int b0   = half * 32;

  // ---- stage x[b0..b0+31][i0..i0+15][0..15], pre-split to bf16 hi|lo ----
  for (int idx = t; idx < 32 * 64; idx += 512) {
    const int bb = idx >> 6, c4 = idx & 63;
    const float4 xv = *reinterpret_cast<const float4*>(
        x + (size_t)(b0 + bb) * (NI * DI) + (size_t)i0 * DI + (c4 << 2));
    uint4 o;
    o.x = pack_split(xv.x); o.y = pack_split(xv.y);
    o.z = pack_split(xv.z); o.w = pack_split(xv.w);
    *reinterpret_cast<uint4*>(&xl[bb * XSTR + (c4 << 2)]) = o;
  }

  // ---- v gather into regs (fixed per lane across i): v[b=col][jd=row(m,r,hb)] ----
  float vreg[4][16];
  if constexpr (ROUTE) {
    #pragma unroll
    for (int m = 0; m < 4; ++m)
      #pragma unroll
      for (int r = 0; r < 16; ++r) {
        const int row = (r & 3) + 8 * (r >> 2) + 4 * hb;
        vreg[m][r] = vin[(size_t)(b0 + col) * JD + wv * 128 + m * 32 + row];
      }
  }

  f32x16 sacc[4];
  #pragma unroll
  for (int m = 0; m < 4; ++m) sacc[m] = zero16();

  __syncthreads();

  if constexpr (!ROUTE) {
    for (int ii = 0; ii < IT; ++ii) {
      // B-frags from LDS (k = hb*8+e), same k-mapping as A side -> permutation-proof
      const uint4 q0 = *reinterpret_cast<const uint4*>(&xl[col * XSTR + (ii << 4) + (hb << 3)]);
      const uint4 q1 = *reinterpret_cast<const uint4*>(&xl[col * XSTR + (ii << 4) + (hb << 3) + 4]);
      bf16x8 xh, xo;
      const uint32_t qq[8] = {q0.x, q0.y, q0.z, q0.w, q1.x, q1.y, q1.z, q1.w};
      #pragma unroll
      for (int e = 0; e < 8; ++e) { xh[e] = (short)(qq[e] >> 16); xo[e] = (short)(qq[e] & 0xffff); }

      const float* wbase = W + (size_t)(i0 + ii) * (JD * DI) + (size_t)wv * 128 * DI;
      #pragma unroll
      for (int m = 0; m < 4; ++m) {
        const float* wt = wbase + m * 32 * DI + col * DI + (hb << 3);
        const float4 wa = *reinterpret_cast<const float4*>(wt);
        const float4 wb = *reinterpret_cast<const float4*>(wt + 4);
        bf16x8 wh, wl; cvt8(wa, wb, wh, wl);
        sacc[m] = __builtin_amdgcn_mfma_f32_32x32x16_bf16(wh, xh, sacc[m], 0, 0, 0);
        sacc[m] = __builtin_amdgcn_mfma_f32_32x32x16_bf16(wh, xo, sacc[m], 0, 0, 0);
        sacc[m] = __builtin_amdgcn_mfma_f32_32x32x16_bf16(wl, xh, sacc[m], 0, 0, 0);
      }
    }
  } else {
    #pragma unroll 1
    for (int ii = 0; ii < IT; ++ii) {
      const uint4 q0 = *reinterpret_cast<const uint4*>(&xl[col * XSTR + (ii << 4) + (hb << 3)]);
      const uint4 q1 = *reinterpret_cast<const uint4*>(&xl[col * XSTR + (ii << 4) + (hb << 3) + 4]);
      bf16x8 xh, xo;
      const uint32_t qq[8] = {q0.x, q0.y, q0.z, q0.w, q1.x, q1.y, q1.z, q1.w};
      #pragma unroll
      for (int e = 0; e < 8; ++e) { xh[e] = (short)(qq[e] >> 16); xo[e] = (short)(qq[e] & 0xffff); }

      const float* wbase = W + (size_t)(i0 + ii) * (JD * DI) + (size_t)wv * 128 * DI;
      f32x16 u[4];
      #pragma unroll
      for (int m = 0; m < 4; ++m) {
        const float* wt = wbase + m * 32 * DI + col * DI + (hb << 3);
        const float4 wa = *reinterpret_cast<const float4*>(wt);
        const float4 wb = *reinterpret_cast<const float4*>(wt + 4);
        bf16x8 wh, wl; cvt8(wa, wb, wh, wl);
        f32x16 c = zero16();
        c = __builtin_amdgcn_mfma_f32_32x32x16_bf16(wh, xh, c, 0, 0, 0);
        c = __builtin_amdgcn_mfma_f32_32x32x16_bf16(wh, xo, c, 0, 0, 0);
        c = __builtin_amdgcn_mfma_f32_32x32x16_bf16(wl, xh, c, 0, 0, 0);
        u[m] = c;
      }

      // agreement a[b, j=wv*4+m] = sum_d u*v ; halves l<->l+32 hold disjoint rows
      float ap[4];
      #pragma unroll
      for (int m = 0; m < 4; ++m) {
        float s = 0.f;
        #pragma unroll
        for (int r = 0; r < 16; ++r) s += u[m][r] * vreg[m][r];
        s += __shfl_xor(s, 32);
        ap[m] = s;
      }
      if (l < 32) {
        #pragma unroll
        for (int m = 0; m < 4; ++m) {
          const int j = (wv << 2) + m;
          al[(j << 5) + ((col + j) & 31)] = ap[m];   // rotation swizzle
        }
      }
      __syncthreads();

      // softmax over j (32) for 32 batches: 512 thr x 2 rounds
      {
        const int jj = t & 31;
        #pragma unroll
        for (int rd = 0; rd < 2; ++rd) {
          const int bb = (t >> 5) + (rd << 4);
          const float av = al[(jj << 5) + ((bb + jj) & 31)];
          float mx = av;
          #pragma unroll
          for (int s = 1; s < 32; s <<= 1) mx = fmaxf(mx, __shfl_xor(mx, s, 32));
          const float e = __expf(av - mx);
          float den = e;
          #pragma unroll
          for (int s = 1; s < 32; s <<= 1) den += __shfl_xor(den, s, 32);
          cl[(jj << 5) + ((bb + jj) & 31)] = e / den;
        }
      }
      __syncthreads();

      #pragma unroll
      for (int m = 0; m < 4; ++m) {
        const int j = (wv << 2) + m;
        const float cv = cl[(j << 5) + ((col + j) & 31)];
        #pragma unroll
        for (int r = 0; r < 16; ++r) sacc[m][r] += cv * u[m][r];
      }
    }
  }

  // ---- epilogue: part[p][b_abs][jd] (L2 write-combined; reduce reads coalesced) ----
  #pragma unroll
  for (int m = 0; m < 4; ++m)
    #pragma unroll
    for (int r = 0; r < 16; ++r) {
      const int jd = (wv << 7) + (m << 5) + (r & 3) + 8 * (r >> 2) + (hb << 2);
      part[((size_t)(p * B_ + b0 + col) << 10) + jd] = sacc[m][r];
    }
}

// out[b,jd] = squash_d(scale * sum_p part[p][b][jd]) [+ vprev]; grid 64 x 1024thr
__global__ void reduce_squash(const float* __restrict__ part, int nPart,
                              const float* __restrict__ vprev,
                              float* __restrict__ out, float scale, int addPrev)
{
  const int b  = blockIdx.x;
  const int jd = threadIdx.x;
  float s = 0.f;
  for (int p = 0; p < nPart; ++p)
    s += part[((size_t)(p * B_ + b) << 10) + jd];
  const float val = s * scale;
  float sq = val * val;
  #pragma unroll
  for (int w = 1; w < 32; w <<= 1) sq += __shfl_xor(sq, w, 32);
  const float f = sq / ((1.0f + sq + EPSQ) * sqrtf(sq + EPSQ));
  float o = f * val;
  if (addPrev) o += vprev[b * JD + jd];
  out[b * JD + jd] = o;
}

extern "C" void kernel_launch(void* const* d_in, const int* in_sizes, int n_in,
                              void* d_out, int out_size, void* d_ws, size_t ws_size,
                              hipStream_t stream) {
  const float* x = (const float*)d_in[0];
  const float* W = (const float*)d_in[1];
  float* ws  = (float*)d_ws;
  float* out = (float*)d_out;

  float* partb = ws;                                   // [128][64][1024] = 32 MB
  float* v0    = ws + (size_t)NBX * B_ * JD;
  float* vs    = v0 + B_ * JD;

  const dim3 grid(NBX, 2);
  // iter 0: uniform c -> s = (1/32) sum_i u_hat
  caps_pass<false><<<grid, 512, 0, stream>>>(x, W, nullptr, partb);
  reduce_squash<<<B_, JD, 0, stream>>>(partb, NBX, nullptr, v0, 1.0f / 32.0f, 0);
  // iter 1: b1 = u.v0
  caps_pass<true><<<grid, 512, 0, stream>>>(x, W, v0, partb);
  reduce_squash<<<B_, JD, 0, stream>>>(partb, NBX, v0, vs, 1.0f, 1);
  // iter 2: b2 = u.(v0+v1)
  caps_pass<true><<<grid, 512, 0, stream>>>(x, W, vs, partb);
  reduce_squash<<<B_, JD, 0, stream>>>(partb, NBX, nullptr, out, 1.0f, 0);
}